// Round 17
// baseline (625.322 us; speedup 1.0000x reference)
//
#include <hip/hip_runtime.h>
#include <math.h>

#define N_BATCH 8
#define IN_CH   256
#define OUT_CH  256
#define T_LEN   2048
#define DKS     33
#define PAD     16
#define KC      16

// conv tiling: block 64o x 128t, 8 waves (512 thr), split-K x4.
// Wave w: K-group kg=w>>1 (chunks kg*2+r, r=0..1), t-half th=w&1.
// Wave tile 64o x 64t (r16-proven inner structure: A global->reg depth-2,
// B from LDS, barrier-free phase loop). Grid (16,4,8)=512 blocks = 2/CU
// = 4 waves/SIMD (r16 was grid-limited to 2/SIMD -> 39% idle).
#define TT 128
#define XS_STRIDE 40   // bf16 elems/row (80B, 16B-aligned)

typedef __attribute__((ext_vector_type(8))) short bf16x8;
typedef __attribute__((ext_vector_type(4))) float f32x4;

__device__ __forceinline__ unsigned short f2bf(float f) {
    unsigned u = __builtin_bit_cast(unsigned, f);
    unsigned r = (u + 0x7FFFu + ((u >> 16) & 1u)) >> 16;   // RNE
    return (unsigned short)r;
}

// ---------------------------------------------------------------------------
// Kernel 1: construct dense conv kernel in bf16, fragment-ready layout:
//   element (o,i,d) at ((g*8 + c)*33 + d)*2048 + a*512 + (q*16+m)*8 + j
//   (g=o>>6, a=(o>>4)&3, m=o&15, c=i>>5, q=(i&31)>>3, j=i&7).
// GATHER formulation (no runtime-indexed array -> no scratch). Faithful
// semantics: frac from out-channel 0; second tap dropped when p1+1 == 33.
// ---------------------------------------------------------------------------
__global__ void build_kern(const float* __restrict__ weight,
                           const float* __restrict__ P,
                           unsigned short* __restrict__ kern_f) {
    int idx = blockIdx.x * blockDim.x + threadIdx.x;   // o*IN_CH + i
    if (idx >= OUT_CH * IN_CH) return;
    int o = idx / IN_CH;
    int i = idx % IN_CH;

    const float* Po = P      + (size_t)(o * IN_CH + i) * KC;
    const float* P0 = P      + (size_t)i * KC;           // out-channel 0
    const float* Wo = weight + (size_t)(o * IN_CH + i) * KC;

    int   p1[KC];
    float w1[KC], w2[KC];
#pragma unroll
    for (int k = 0; k < KC; ++k) {
        float pp = Po[k] + (float)(DKS / 2);
        float p0 = P0[k] + (float)(DKS / 2);
        float fr = p0 - floorf(p0);
        float w  = Wo[k];
        p1[k] = (int)floorf(pp);
        w1[k] = w * (1.0f - fr);
        w2[k] = w * fr;
    }

    int g  = o >> 6;
    int ai = (o >> 4) & 3;
    int m  = o & 15;
    int c  = i >> 5;
    int il = i & 31;
    int q  = il >> 3;
    int j  = il & 7;
    size_t base = ((size_t)(g * 8 + c) * 33) * 2048
                + (size_t)ai * 512 + (size_t)(q * 16 + m) * 8 + j;

#pragma unroll
    for (int d = 0; d < DKS; ++d) {
        float acc = 0.0f;
#pragma unroll
        for (int k = 0; k < KC; ++k) {
            acc += (p1[k] == d)     ? w1[k] : 0.0f;
            acc += (p1[k] == d - 1) ? w2[k] : 0.0f;
        }
        kern_f[base + (size_t)d * 2048] = f2bf(acc);
    }
}

// ---------------------------------------------------------------------------
// Kernel 2 (r16 + occupancy): split-K x4, 2 blocks/CU, 4 waves/SIMD.
//  - Inner phase loop identical to r16 (A reg-prefetch depth 2, B from LDS,
//    no per-phase barriers, setprio around MFMA cluster).
//  - Xs: 4 K-group copies (51.2KB), staged SYNCHRONOUSLY per round (frees
//    the 20 xv regs so VGPR fits 128 -> both blocks resident).
//  - 2 rounds (each kg owns chunks kg*2+0, kg*2+1).
//  - Reduce: 2-step 4-way LDS tree (r13 pattern), smem 64KB reused.
// ---------------------------------------------------------------------------
__global__ __launch_bounds__(512, 4) void dcls_conv(
    const float* __restrict__ x,
    const unsigned short* __restrict__ kern_f,
    const float* __restrict__ bias,
    float* __restrict__ out)
{
    __shared__ __align__(16) unsigned char smem[65536];   // Xs[4][160*40]u16 (51.2KB) / reduce 64KB
    unsigned short* XsB = (unsigned short*)smem;

    const int t0    = blockIdx.x * TT;
    const int o0    = blockIdx.y * 64;
    const int batch = blockIdx.z;

    const int tid  = threadIdx.x;
    const int w    = tid >> 6;        // wave 0..7
    const int l    = tid & 63;
    const int quad = l >> 4;
    const int lm   = l & 15;
    const int kg   = w >> 1;          // K-group 0..3
    const int th   = w & 1;           // t-half
    const int wt   = th * 64;         // t-base (local)

    bf16x8 apre[3][4];                // 3-buffer rotating A prefetch (depth 2)

    f32x4 acc[4][4];
#pragma unroll
    for (int a = 0; a < 4; ++a)
#pragma unroll
        for (int b = 0; b < 4; ++b) acc[a][b] = (f32x4){0.f, 0.f, 0.f, 0.f};

    // synchronous Xs staging for round R: 4 K-groups x 32i x 160t
#define XSTAGE(R)                                                             \
    do {                                                                      \
        const int rr_ = (R);                                                  \
        _Pragma("unroll")                                                     \
        for (int it = 0; it < 20; ++it) {                                     \
            int idx = tid + it * 512;          /* 0..10239 */                 \
            int kgs = idx / 2560;              /* K-group 0..3 */             \
            int rem = idx - kgs * 2560;                                       \
            int ip  = rem / 160;               /* i-pair 0..15 */             \
            int t   = rem - ip * 160;          /* 0..159 */                   \
            int gg  = t0 - PAD + t;                                           \
            float v0 = 0.f, v1 = 0.f;                                         \
            if ((unsigned)gg < (unsigned)T_LEN) {                             \
                const float* xb = x + ((size_t)(batch * IN_CH                 \
                                 + (kgs * 2 + rr_) * 32 + ip * 2) * T_LEN) + gg; \
                v0 = xb[0];                                                   \
                v1 = xb[T_LEN];                                               \
            }                                                                 \
            unsigned pk = (unsigned)f2bf(v0) | ((unsigned)f2bf(v1) << 16);    \
            *(unsigned*)(&XsB[kgs * 6400 + t * XS_STRIDE + ip * 2]) = pk;     \
        }                                                                     \
    } while (0)

    // load the 4 A-frags for depth-slot D into apre[NB] (coalesced 4x1KB)
#define ALOAD(NB, D)                                                          \
    do {                                                                      \
        _Pragma("unroll")                                                     \
        for (int a = 0; a < 4; ++a)                                           \
            apre[NB][a] = *(const bf16x8*)(kab + (size_t)(D) * 2048 + a * 512); \
    } while (0)

    // one d: 4 B-reads from own K-group's Xs, 16 MFMA on apre[NB]
#define PHASE(NB, D)                                                          \
    do {                                                                      \
        bf16x8 bfr[4];                                                        \
        _Pragma("unroll")                                                     \
        for (int b = 0; b < 4; ++b)                                           \
            bfr[b] = *(const bf16x8*)(&XsB[kg * 6400                          \
                + (wt + b * 16 + lm + (D)) * XS_STRIDE + quad * 8]);          \
        __builtin_amdgcn_s_setprio(1);                                        \
        _Pragma("unroll")                                                     \
        for (int a = 0; a < 4; ++a)                                           \
            _Pragma("unroll")                                                 \
            for (int b = 0; b < 4; ++b)                                       \
                acc[a][b] = __builtin_amdgcn_mfma_f32_16x16x32_bf16(          \
                    apre[NB][a], bfr[b], acc[a][b], 0, 0, 0);                 \
        __builtin_amdgcn_s_setprio(0);                                        \
    } while (0)

    for (int r = 0; r < 2; ++r) {
        __syncthreads();           // previous round's Xs reads done
        XSTAGE(r);
        __syncthreads();           // Xs published

        // this wave's A base: o-group = blockIdx.y, chunk = kg*2+r
        const unsigned short* kab = kern_f
            + ((size_t)(blockIdx.y * 8 + kg * 2 + r) * 33) * 2048
            + (size_t)l * 8;

        ALOAD(0, 0);
        ALOAD(1, 1);

        // ---- 33 barrier-free phases, depth-2 register A-pipeline ----
#pragma unroll
        for (int d = 0; d < 33; ++d) {
            if (d < 31) ALOAD((d + 2) % 3, d + 2);
            PHASE(d % 3, d);
        }
    }
#undef XSTAGE
#undef ALOAD
#undef PHASE

    // ---- split-K x4 reduce (smem as 4 x 64x64 f32 slots) + epilogue ----
    __syncthreads();
    float* red = (float*)smem;
    // step 1: kg 2,3 publish
    if (kg >= 2) {
        const int slot = th * 2 + (kg - 2);
#pragma unroll
        for (int a = 0; a < 4; ++a)
#pragma unroll
            for (int b = 0; b < 4; ++b)
#pragma unroll
                for (int r2 = 0; r2 < 4; ++r2)
                    red[slot * 4096 + (a * 16 + quad * 4 + r2) * 64 + b * 16 + lm]
                        = acc[a][b][r2];
    }
    __syncthreads();
    // step 2: kg 0,1 absorb kg+2's partial
    if (kg < 2) {
        const int slot = th * 2 + kg;
#pragma unroll
        for (int a = 0; a < 4; ++a)
#pragma unroll
            for (int b = 0; b < 4; ++b)
#pragma unroll
                for (int r2 = 0; r2 < 4; ++r2)
                    acc[a][b][r2] +=
                        red[slot * 4096 + (a * 16 + quad * 4 + r2) * 64 + b * 16 + lm];
    }
    __syncthreads();
    // step 3: kg 1 publishes its sum
    if (kg == 1) {
        const int slot = th * 2;
#pragma unroll
        for (int a = 0; a < 4; ++a)
#pragma unroll
            for (int b = 0; b < 4; ++b)
#pragma unroll
                for (int r2 = 0; r2 < 4; ++r2)
                    red[slot * 4096 + (a * 16 + quad * 4 + r2) * 64 + b * 16 + lm]
                        = acc[a][b][r2];
    }
    __syncthreads();
    // step 4: kg 0 finishes + bias + store
    if (kg == 0) {
        const int slot = th * 2;
#pragma unroll
        for (int a = 0; a < 4; ++a) {
#pragma unroll
            for (int r2 = 0; r2 < 4; ++r2) {
                int o = o0 + a * 16 + quad * 4 + r2;
                float bv = bias[o];
                float* orow = out + ((size_t)(batch * OUT_CH + o) * T_LEN) + t0 + wt + lm;
#pragma unroll
                for (int b = 0; b < 4; ++b)
                    orow[b * 16] = acc[a][b][r2]
                        + red[slot * 4096 + (a * 16 + quad * 4 + r2) * 64 + b * 16 + lm]
                        + bv;
            }
        }
    }
}

extern "C" void kernel_launch(void* const* d_in, const int* in_sizes, int n_in,
                              void* d_out, int out_size, void* d_ws, size_t ws_size,
                              hipStream_t stream) {
    const float* x      = (const float*)d_in[0];
    const float* weight = (const float*)d_in[1];
    const float* P      = (const float*)d_in[2];
    const float* bias   = (const float*)d_in[3];
    float*       out    = (float*)d_out;
    unsigned short* kern_f = (unsigned short*)d_ws;   // 256*256*33 bf16 = 4.33MB

    hipLaunchKernelGGL(build_kern,
                       dim3((OUT_CH * IN_CH + 255) / 256), dim3(256), 0, stream,
                       weight, P, kern_f);

    // block tile 64o x 128t, split-K x4; grid (16,4,8) = 512 blocks = 2/CU
    dim3 grid(T_LEN / TT, OUT_CH / 64, N_BATCH);
    hipLaunchKernelGGL(dcls_conv, grid, dim3(512), 0, stream,
                       x, kern_f, bias, out);
}